// Round 7
// baseline (392.058 us; speedup 1.0000x reference)
//
#include <hip/hip_runtime.h>

#define HH 512
#define WW 512
#define HW (HH * WW)

typedef float f32x4 __attribute__((ext_vector_type(4)));

// ---------------- Pass 1: pool + last-block SEKG head ----------------
// grid = 512 planes * 4 strips, block = 256 threads. float4 loads.
// The last block to finish (atomic counter) computes the 8 per-sample
// 3x3 taps into kout — removes the 1-block middle kernel and its two
// pipeline drains.
__global__ __launch_bounds__(256) void pool_kernel(const float* __restrict__ x,
                                                   float* __restrict__ partial,
                                                   int* __restrict__ counter,
                                                   const float* __restrict__ w1,
                                                   const float* __restrict__ b1,
                                                   const float* __restrict__ w2,
                                                   const float* __restrict__ b2,
                                                   float* __restrict__ kout) {
    const int blk = blockIdx.x;
    const int plane = blk >> 2;
    const int strip = blk & 3;
    const int t = threadIdx.x;
    const float4* p = reinterpret_cast<const float4*>(x + (size_t)plane * HW) +
                      (size_t)strip * (HW / 16);
    float s = 0.f;
    #pragma unroll 4
    for (int i = t; i < HW / 16; i += 256) {
        float4 v = p[i];
        s += (v.x + v.y) + (v.z + v.w);
    }
    #pragma unroll
    for (int off = 32; off > 0; off >>= 1) s += __shfl_down(s, off, 64);
    __shared__ float wsum[4];
    __shared__ int lastFlag;
    const int lane = t & 63;
    const int wid  = t >> 6;
    if (lane == 0) wsum[wid] = s;
    __syncthreads();
    if (t == 0) {
        partial[blk] = (wsum[0] + wsum[1]) + (wsum[2] + wsum[3]);
        __threadfence();                       // release partial[blk]
        int c = atomicAdd(counter, 1);         // device-scope
        lastFlag = (c == 2047);
    }
    __syncthreads();
    if (!lastFlag) return;

    // ---- last block: compute taps for all 8 batches ----
    __threadfence();                           // acquire all partials
    __shared__ float feat[512];                // [b][c]
    __shared__ float h1s[512];                 // [b][c]
    __shared__ float kr[72];                   // [b][9]
    __shared__ float ksm[8];
    #pragma unroll
    for (int r = t; r < 512; r += 256)
        feat[r] = (partial[4*r] + partial[4*r+1] + partial[4*r+2] + partial[4*r+3]) *
                  (1.0f / (float)HW);
    __syncthreads();
    #pragma unroll
    for (int r = t; r < 512; r += 256) {
        const int b = r >> 6, j = r & 63;
        float h = b1[j];
        const float* wr = w1 + j * 64;
        const float* fb = feat + b * 64;
        #pragma unroll 8
        for (int c = 0; c < 64; ++c) h += fb[c] * wr[c];
        h1s[r] = (h > 0.f) ? h : 0.2f * h;     // LeakyReLU(0.2)
    }
    __syncthreads();
    if (t < 72) {
        const int bb = t / 9, q = t - bb * 9;
        float s2 = b2[q];
        const float* hb = h1s + bb * 64;
        const float* wq = w2 + q * 64;
        #pragma unroll 8
        for (int c = 0; c < 64; ++c) s2 += hb[c] * wq[c];
        kr[t] = s2;
    }
    __syncthreads();
    if (t < 8) {
        float s3 = 0.f;
        #pragma unroll
        for (int q = 0; q < 9; ++q) s3 += kr[t * 9 + q];
        ksm[t] = s3 + 1e-6f;
    }
    __syncthreads();
    if (t < 72) kout[t] = kr[t] / ksm[t / 9];
}

// ---------------- Pass 2: depthwise 3x3 conv (identical to R3) ----------------
__device__ __forceinline__ void load_row6(float r[6], const float* __restrict__ plane,
                                          int y, int x0) {
    if ((unsigned)y >= (unsigned)HH) {
        r[0] = r[1] = r[2] = r[3] = r[4] = r[5] = 0.f;
        return;
    }
    const float* row = plane + (size_t)y * WW;
    r[0] = (x0 > 0) ? row[x0 - 1] : 0.f;
    const float4 m = *reinterpret_cast<const float4*>(row + x0);
    r[1] = m.x; r[2] = m.y; r[3] = m.z; r[4] = m.w;
    r[5] = (x0 + 4 < WW) ? row[x0 + 4] : 0.f;
}

__global__ __launch_bounds__(256) void conv_kernel(const float* __restrict__ x,
                                                   const float* __restrict__ kall,
                                                   float* __restrict__ out) {
    const int gid    = blockIdx.x * 256 + threadIdx.x;
    const int xseg   = gid & 127;          // 128 quads of 4 -> 512 wide
    const int ystrip = (gid >> 7) & 31;    // 32 strips of 16 rows
    const int plane  = gid >> 12;          // b*64 + c
    const int b      = plane >> 6;
    float k[9];
    #pragma unroll
    for (int i = 0; i < 9; ++i) k[i] = kall[b * 9 + i];
    const float* xp = x + (size_t)plane * HW;
    float* op       = out + (size_t)plane * HW;
    const int x0 = xseg * 4;
    const int y0 = ystrip * 16;

    float r0[6], r1[6], r2[6];
    load_row6(r0, xp, y0 - 1, x0);
    load_row6(r1, xp, y0,     x0);
    #pragma unroll
    for (int i = 0; i < 16; ++i) {
        load_row6(r2, xp, y0 + i + 1, x0);
        f32x4 o;
        #pragma unroll
        for (int j = 0; j < 4; ++j) {
            o[j] = k[0]*r0[j] + k[1]*r0[j+1] + k[2]*r0[j+2]
                 + k[3]*r1[j] + k[4]*r1[j+1] + k[5]*r1[j+2]
                 + k[6]*r2[j] + k[7]*r2[j+1] + k[8]*r2[j+2];
        }
        __builtin_nontemporal_store(o,
            reinterpret_cast<f32x4*>(op + (size_t)(y0 + i) * WW + x0));
        #pragma unroll
        for (int q = 0; q < 6; ++q) { r0[q] = r1[q]; r1[q] = r2[q]; }
    }
}

extern "C" void kernel_launch(void* const* d_in, const int* in_sizes, int n_in,
                              void* d_out, int out_size, void* d_ws, size_t ws_size,
                              hipStream_t stream) {
    const float* x  = (const float*)d_in[0];
    const float* w1 = (const float*)d_in[1];
    const float* b1 = (const float*)d_in[2];
    const float* w2 = (const float*)d_in[3];
    const float* b2 = (const float*)d_in[4];
    float* out = (float*)d_out;

    float* partial = (float*)d_ws;        // 2048 floats
    float* kout    = partial + 2048;      // 72 floats
    int*   counter = (int*)(partial + 2048 + 128);  // 1 int, aligned

    hipMemsetAsync(counter, 0, sizeof(int), stream);
    pool_kernel<<<2048, 256, 0, stream>>>(x, partial, counter, w1, b1, w2, b2, kout);
    conv_kernel<<<8192, 256, 0, stream>>>(x, kout, out);
}

// Round 9
// 288.879 us; speedup vs baseline: 1.3572x; 1.3572x over previous
//
#include <hip/hip_runtime.h>

#define HH 512
#define WW 512
#define HW (HH * WW)

typedef float f32x4 __attribute__((ext_vector_type(4)));

// ---------------- Pass 1: partial sums per (plane, strip) ----------------
// grid = 512 planes * 4 strips, block = 256 threads. float4 loads.
__global__ __launch_bounds__(256) void pool_kernel(const float* __restrict__ x,
                                                   float* __restrict__ partial) {
    const int blk = blockIdx.x;
    const int plane = blk >> 2;
    const int strip = blk & 3;
    const float4* p = reinterpret_cast<const float4*>(x + (size_t)plane * HW) +
                      (size_t)strip * (HW / 16);
    float s = 0.f;
    #pragma unroll 4
    for (int i = threadIdx.x; i < HW / 16; i += 256) {
        float4 v = p[i];
        s += (v.x + v.y) + (v.z + v.w);
    }
    #pragma unroll
    for (int off = 32; off > 0; off >>= 1) s += __shfl_down(s, off, 64);
    __shared__ float wsum[4];
    const int lane = threadIdx.x & 63;
    const int wid  = threadIdx.x >> 6;
    if (lane == 0) wsum[wid] = s;
    __syncthreads();
    if (threadIdx.x == 0) partial[blk] = (wsum[0] + wsum[1]) + (wsum[2] + wsum[3]);
}

// ---------------- Pass 2: tiny SEKG head, one block ----------------
__global__ __launch_bounds__(512) void make_kernels(const float* __restrict__ partial,
                                                    const float* __restrict__ w1,
                                                    const float* __restrict__ b1,
                                                    const float* __restrict__ w2,
                                                    const float* __restrict__ b2,
                                                    float* __restrict__ kout) {
    __shared__ float feat[512];  // [b][c]
    __shared__ float h1[512];    // [b][c]
    __shared__ float kr[72];     // [b][9]
    __shared__ float ksum[8];
    const int t = threadIdx.x;  // 0..511
    feat[t] = (partial[4*t] + partial[4*t+1] + partial[4*t+2] + partial[4*t+3]) *
              (1.0f / (float)HW);
    __syncthreads();
    const int b = t >> 6, j = t & 63;
    float s = b1[j];
    const float* wr = w1 + j * 64;
    const float* fb = feat + b * 64;
    #pragma unroll 8
    for (int c = 0; c < 64; ++c) s += fb[c] * wr[c];
    h1[t] = (s > 0.f) ? s : 0.2f * s;  // LeakyReLU(0.2)
    __syncthreads();
    if (t < 72) {
        const int bb = t / 9, q = t - bb * 9;
        float s2 = b2[q];
        const float* hb = h1 + bb * 64;
        const float* wq = w2 + q * 64;
        #pragma unroll 8
        for (int c = 0; c < 64; ++c) s2 += hb[c] * wq[c];
        kr[t] = s2;
    }
    __syncthreads();
    if (t < 8) {
        float s3 = 0.f;
        #pragma unroll
        for (int q = 0; q < 9; ++q) s3 += kr[t * 9 + q];
        ksum[t] = s3 + 1e-6f;
    }
    __syncthreads();
    if (t < 72) kout[t] = kr[t] / ksum[t / 9];
}

// ---------------- Pass 3: depthwise 3x3 conv, banded ----------------
// 1024 blocks; each block owns a 256-row half-plane and sweeps 8
// vertically-contiguous 32-row bands. Halo rows between consecutive bands
// are L1/L2-hot on the same CU (R3's cross-block halos were HBM re-fetches).
// Thread = 4 wide x 16 tall; t>>7 picks the 16-row group within a band.
__device__ __forceinline__ void load_row6(float r[6], const float* __restrict__ plane,
                                          int y, int x0) {
    if ((unsigned)y >= (unsigned)HH) {
        r[0] = r[1] = r[2] = r[3] = r[4] = r[5] = 0.f;
        return;
    }
    const float* row = plane + (size_t)y * WW;
    r[0] = (x0 > 0) ? row[x0 - 1] : 0.f;
    const float4 m = *reinterpret_cast<const float4*>(row + x0);
    r[1] = m.x; r[2] = m.y; r[3] = m.z; r[4] = m.w;
    r[5] = (x0 + 4 < WW) ? row[x0 + 4] : 0.f;
}

__global__ __launch_bounds__(256) void conv_kernel(const float* __restrict__ x,
                                                   const float* __restrict__ kall,
                                                   float* __restrict__ out) {
    const int blk   = blockIdx.x;        // 0..1023
    const int t     = threadIdx.x;
    const int plane = blk >> 1;          // b*64 + c
    const int halfv = blk & 1;           // which 256-row half
    const int b     = plane >> 6;
    float k[9];
    #pragma unroll
    for (int i = 0; i < 9; ++i) k[i] = kall[b * 9 + i];
    const float* xp = x + (size_t)plane * HW;
    float* op       = out + (size_t)plane * HW;
    const int x0 = (t & 127) * 4;
    const int tg = t >> 7;               // 0/1: 16-row group within band

    #pragma unroll
    for (int vb = 0; vb < 8; ++vb) {
        const int y0 = halfv * 256 + vb * 32 + tg * 16;
        float r0[6], r1[6], r2[6];
        load_row6(r0, xp, y0 - 1, x0);
        load_row6(r1, xp, y0,     x0);
        #pragma unroll
        for (int i = 0; i < 16; ++i) {
            load_row6(r2, xp, y0 + i + 1, x0);
            f32x4 o;
            #pragma unroll
            for (int j = 0; j < 4; ++j) {
                o[j] = k[0]*r0[j] + k[1]*r0[j+1] + k[2]*r0[j+2]
                     + k[3]*r1[j] + k[4]*r1[j+1] + k[5]*r1[j+2]
                     + k[6]*r2[j] + k[7]*r2[j+1] + k[8]*r2[j+2];
            }
            __builtin_nontemporal_store(o,
                reinterpret_cast<f32x4*>(op + (size_t)(y0 + i) * WW + x0));
            #pragma unroll
            for (int q = 0; q < 6; ++q) { r0[q] = r1[q]; r1[q] = r2[q]; }
        }
    }
}

extern "C" void kernel_launch(void* const* d_in, const int* in_sizes, int n_in,
                              void* d_out, int out_size, void* d_ws, size_t ws_size,
                              hipStream_t stream) {
    const float* x  = (const float*)d_in[0];
    const float* w1 = (const float*)d_in[1];
    const float* b1 = (const float*)d_in[2];
    const float* w2 = (const float*)d_in[3];
    const float* b2 = (const float*)d_in[4];
    float* out = (float*)d_out;

    float* partial = (float*)d_ws;      // 2048 floats
    float* kout    = partial + 2048;    // 72 floats

    pool_kernel<<<2048, 256, 0, stream>>>(x, partial);
    make_kernels<<<1, 512, 0, stream>>>(partial, w1, b1, w2, b2, kout);
    conv_kernel<<<1024, 256, 0, stream>>>(x, kout, out);
}